// Round 1
// baseline (268.380 us; speedup 1.0000x reference)
//
#include <hip/hip_runtime.h>

#define IMG_H 512
#define IMG_W 512
#define NPLANES 48            // 16 batch * 3 channels
#define N_ELEMS (16 * 3 * 512 * 512)

#define TW 32
#define TH 32
#define HALO 5
#define KS 11
#define SW (TW + 2 * HALO)    // 42
#define SH (TH + 2 * HALO)    // 42
#define NTHREADS 256

#define C1 1.0e-4f            // 0.01^2
#define C2 9.0e-4f            // 0.03^2

__global__ void ssim_init(float* ws) { ws[0] = 0.0f; }

__global__ void __launch_bounds__(NTHREADS) ssim_main(
    const float* __restrict__ img1, const float* __restrict__ img2,
    float* __restrict__ ws)
{
    __shared__ float s1[SH][SW];
    __shared__ float s2[SH][SW];
    __shared__ float r[5][TH][SW];     // vertical-pass results: mu1,mu2,e11,e22,e12
    __shared__ float wpart[NTHREADS / 64];

    const int tid = threadIdx.x;
    const int plane = blockIdx.z;
    const int ty0 = blockIdx.y * TH;
    const int tx0 = blockIdx.x * TW;
    const float* p1 = img1 + (size_t)plane * IMG_H * IMG_W;
    const float* p2 = img2 + (size_t)plane * IMG_H * IMG_W;

    // Gaussian window, normalized (matches reference: exp(-d^2/(2*1.5^2)) / sum)
    float g[KS];
    {
        float s = 0.0f;
#pragma unroll
        for (int i = 0; i < KS; ++i) {
            float d = (float)(i - KS / 2);
            g[i] = expf(-(d * d) / 4.5f);
            s += g[i];
        }
        float inv = 1.0f / s;
#pragma unroll
        for (int i = 0; i < KS; ++i) g[i] *= inv;
    }

    // ---- Stage both images (tile + halo) into LDS, zero-padded at borders ----
    for (int i = tid; i < SH * SW; i += NTHREADS) {
        int sy = i / SW;
        int sx = i - sy * SW;
        int gy = ty0 + sy - HALO;
        int gx = tx0 + sx - HALO;
        float a = 0.0f, b = 0.0f;
        if (gy >= 0 && gy < IMG_H && gx >= 0 && gx < IMG_W) {
            size_t idx = (size_t)gy * IMG_W + gx;
            a = p1[idx];
            b = p2[idx];
        }
        s1[sy][sx] = a;
        s2[sy][sx] = b;
    }
    __syncthreads();

    // ---- Vertical pass: r[q][y][x] = sum_k g[k] * f(s[y+k][x]) ----
    // Register-tiled: each active thread produces 8 consecutive y outputs at one x.
    if (tid < 4 * SW) {                 // 168 active threads
        int x = tid % SW;
        int y0 = (tid / SW) * 8;
        float acc[8][5];
#pragma unroll
        for (int k = 0; k < 8; ++k)
#pragma unroll
            for (int q = 0; q < 5; ++q) acc[k][q] = 0.0f;

#pragma unroll
        for (int j = 0; j < 8 + KS - 1; ++j) {   // 18 staged rows feed 8 outputs
            float a = s1[y0 + j][x];
            float b = s2[y0 + j][x];
            float aa = a * a, bb = b * b, ab = a * b;
#pragma unroll
            for (int k = 0; k < 8; ++k) {
                int t = j - k;
                if (t >= 0 && t < KS) {
                    float w = g[t];
                    acc[k][0] += w * a;
                    acc[k][1] += w * b;
                    acc[k][2] += w * aa;
                    acc[k][3] += w * bb;
                    acc[k][4] += w * ab;
                }
            }
        }
#pragma unroll
        for (int k = 0; k < 8; ++k)
#pragma unroll
            for (int q = 0; q < 5; ++q) r[q][y0 + k][x] = acc[k][q];
    }
    __syncthreads();

    // ---- Horizontal pass + SSIM map + local sum ----
    // Register-tiled: each active thread produces 8 consecutive x outputs at one y.
    float local = 0.0f;
    if (tid < TH * (TW / 8)) {          // 128 active threads
        int y = tid >> 2;
        int x0 = (tid & 3) * 8;
        float o[8][5];
#pragma unroll
        for (int k = 0; k < 8; ++k)
#pragma unroll
            for (int q = 0; q < 5; ++q) o[k][q] = 0.0f;

#pragma unroll
        for (int j = 0; j < 8 + KS - 1; ++j) {   // 18 columns feed 8 outputs
            float v0 = r[0][y][x0 + j];
            float v1 = r[1][y][x0 + j];
            float v2 = r[2][y][x0 + j];
            float v3 = r[3][y][x0 + j];
            float v4 = r[4][y][x0 + j];
#pragma unroll
            for (int k = 0; k < 8; ++k) {
                int t = j - k;
                if (t >= 0 && t < KS) {
                    float w = g[t];
                    o[k][0] += w * v0;
                    o[k][1] += w * v1;
                    o[k][2] += w * v2;
                    o[k][3] += w * v3;
                    o[k][4] += w * v4;
                }
            }
        }
#pragma unroll
        for (int k = 0; k < 8; ++k) {
            float mu1 = o[k][0], mu2 = o[k][1];
            float mu1s = mu1 * mu1, mu2s = mu2 * mu2, mu12 = mu1 * mu2;
            float sg11 = o[k][2] - mu1s;
            float sg22 = o[k][3] - mu2s;
            float sg12 = o[k][4] - mu12;
            float num = (2.0f * mu12 + C1) * (2.0f * sg12 + C2);
            float den = (mu1s + mu2s + C1) * (sg11 + sg22 + C2);
            local += num / den;
        }
    }

    // ---- Block reduction: wave shuffle -> LDS -> one atomic per block ----
#pragma unroll
    for (int off = 32; off > 0; off >>= 1) local += __shfl_down(local, off, 64);
    if ((tid & 63) == 0) wpart[tid >> 6] = local;
    __syncthreads();
    if (tid == 0) {
        float t = wpart[0] + wpart[1] + wpart[2] + wpart[3];
        atomicAdd(ws, t);
    }
}

__global__ void ssim_final(const float* __restrict__ ws, float* __restrict__ out) {
    out[0] = 1.0f - ws[0] * (1.0f / (float)N_ELEMS);
}

extern "C" void kernel_launch(void* const* d_in, const int* in_sizes, int n_in,
                              void* d_out, int out_size, void* d_ws, size_t ws_size,
                              hipStream_t stream) {
    const float* img1 = (const float*)d_in[0];
    const float* img2 = (const float*)d_in[1];
    float* out = (float*)d_out;
    float* acc = (float*)d_ws;

    ssim_init<<<1, 1, 0, stream>>>(acc);
    dim3 grid(IMG_W / TW, IMG_H / TH, NPLANES);
    ssim_main<<<grid, NTHREADS, 0, stream>>>(img1, img2, acc);
    ssim_final<<<1, 1, 0, stream>>>(acc, out);
}

// Round 2
// 178.058 us; speedup vs baseline: 1.5073x; 1.5073x over previous
//
#include <hip/hip_runtime.h>

#define IMG_H 512
#define IMG_W 512
#define NPLANES 48            // 16 batch * 3 channels
#define N_ELEMS (16 * 3 * 512 * 512)

#define TW 32
#define TH 32
#define HALO 5
#define KS 11
#define SW (TW + 2 * HALO)    // 42 (logical)
#define SH (TH + 2 * HALO)    // 42
#define LSTRIDE 43            // padded LDS row stride (odd -> conflict-free-ish)
#define NTHREADS 256
#define GX (IMG_W / TW)       // 16
#define GY (IMG_H / TH)       // 16
#define NBLOCKS (GX * GY * NPLANES)   // 12288

#define C1 1.0e-4f            // 0.01^2
#define C2 9.0e-4f            // 0.03^2

// LDS: staging (s=a+b, d=a-b) overlaid with vertical-conv results.
// Vertical results live in registers across the barrier between phases,
// so the two uses never coexist. 22.0 KB -> ~6 blocks/CU (vs 41.5 KB / 3).
union SsimLds {
    float stage[2][SH][LSTRIDE];      // 14.4 KB: [0]=s, [1]=d
    float r[4][TH][LSTRIDE];          // 22.0 KB: conv_y of {s, d, s^2, d^2}
};

__global__ void __launch_bounds__(NTHREADS, 6) ssim_main(
    const float* __restrict__ img1, const float* __restrict__ img2,
    float* __restrict__ partials)
{
    __shared__ SsimLds u;
    __shared__ float wpart[NTHREADS / 64];

    const int tid = threadIdx.x;
    const int plane = blockIdx.z;
    const int ty0 = blockIdx.y * TH;
    const int tx0 = blockIdx.x * TW;
    const float* p1 = img1 + (size_t)plane * IMG_H * IMG_W;
    const float* p2 = img2 + (size_t)plane * IMG_H * IMG_W;

    // Gaussian window, normalized (matches reference: exp(-d^2/(2*1.5^2)) / sum)
    float g[KS];
    {
        float s = 0.0f;
#pragma unroll
        for (int i = 0; i < KS; ++i) {
            float d = (float)(i - KS / 2);
            g[i] = expf(-(d * d) / 4.5f);
            s += g[i];
        }
        float inv = 1.0f / s;
#pragma unroll
        for (int i = 0; i < KS; ++i) g[i] *= inv;
    }

    // ---- Stage s = a+b, d = a-b (tile + halo), zero-padded at borders ----
    for (int i = tid; i < SH * SW; i += NTHREADS) {
        int sy = i / SW;
        int sx = i - sy * SW;
        int gy = ty0 + sy - HALO;
        int gx = tx0 + sx - HALO;
        float a = 0.0f, b = 0.0f;
        if ((unsigned)gy < IMG_H && (unsigned)gx < IMG_W) {
            size_t idx = (size_t)gy * IMG_W + gx;
            a = p1[idx];
            b = p2[idx];
        }
        u.stage[0][sy][sx] = a + b;
        u.stage[1][sy][sx] = a - b;
    }
    __syncthreads();

    // ---- Vertical pass into REGISTERS: acc[k][q], q over {s,d,s^2,d^2} ----
    // 168 active threads: x = tid%42, 4 row-groups of 8 outputs.
    const bool vact = tid < 4 * SW;
    const int vx = tid % SW;
    const int vy0 = (tid / SW) * 8;
    float acc[8][4];
    if (vact) {
#pragma unroll
        for (int k = 0; k < 8; ++k)
#pragma unroll
            for (int q = 0; q < 4; ++q) acc[k][q] = 0.0f;
#pragma unroll
        for (int j = 0; j < 8 + KS - 1; ++j) {       // 18 staged rows
            float sv = u.stage[0][vy0 + j][vx];
            float dv = u.stage[1][vy0 + j][vx];
            float ss = sv * sv, dd = dv * dv;
#pragma unroll
            for (int k = 0; k < 8; ++k) {
                int t = j - k;
                if (t >= 0 && t < KS) {              // folds at compile time
                    float w = g[t];
                    acc[k][0] += w * sv;
                    acc[k][1] += w * dv;
                    acc[k][2] += w * ss;
                    acc[k][3] += w * dd;
                }
            }
        }
    }
    __syncthreads();    // all stage reads done -> safe to overwrite with r

    if (vact) {
#pragma unroll
        for (int k = 0; k < 8; ++k)
#pragma unroll
            for (int q = 0; q < 4; ++q) u.r[q][vy0 + k][vx] = acc[k][q];
    }
    __syncthreads();

    // ---- Horizontal pass + SSIM + local sum: 256 threads x 4 outputs ----
    const int hy = tid >> 3;            // 0..31
    const int hx0 = (tid & 7) * 4;      // 0,4,...,28
    float o[4][4];
#pragma unroll
    for (int k = 0; k < 4; ++k)
#pragma unroll
        for (int q = 0; q < 4; ++q) o[k][q] = 0.0f;

#pragma unroll
    for (int j = 0; j < 4 + KS - 1; ++j) {           // 14 columns
        float v0 = u.r[0][hy][hx0 + j];
        float v1 = u.r[1][hy][hx0 + j];
        float v2 = u.r[2][hy][hx0 + j];
        float v3 = u.r[3][hy][hx0 + j];
#pragma unroll
        for (int k = 0; k < 4; ++k) {
            int t = j - k;
            if (t >= 0 && t < KS) {
                float w = g[t];
                o[k][0] += w * v0;
                o[k][1] += w * v1;
                o[k][2] += w * v2;
                o[k][3] += w * v3;
            }
        }
    }

    float local = 0.0f;
#pragma unroll
    for (int k = 0; k < 4; ++k) {
        float cs = o[k][0], cd = o[k][1], css = o[k][2], cdd = o[k][3];
        float cs2 = cs * cs, cd2 = cd * cd;
        float mu12 = 0.25f * (cs2 - cd2);     // mu1*mu2
        float musq = 0.50f * (cs2 + cd2);     // mu1^2 + mu2^2
        float e12  = 0.25f * (css - cdd);     // E[ab]
        float esum = 0.50f * (css + cdd);     // E[a^2] + E[b^2]
        float sg12  = e12 - mu12;
        float sgsum = esum - musq;
        float num = (2.0f * mu12 + C1) * (2.0f * sg12 + C2);
        float den = (musq + C1) * (sgsum + C2);
        local += num / den;
    }

    // ---- Block reduction -> one partial per block (no init kernel) ----
#pragma unroll
    for (int off = 32; off > 0; off >>= 1) local += __shfl_down(local, off, 64);
    if ((tid & 63) == 0) wpart[tid >> 6] = local;
    __syncthreads();
    if (tid == 0) {
        int bid = blockIdx.x + GX * (blockIdx.y + GY * blockIdx.z);
        partials[bid] = wpart[0] + wpart[1] + wpart[2] + wpart[3];
    }
}

__global__ void ssim_final(const float* __restrict__ partials,
                           float* __restrict__ out)
{
    __shared__ float wp[4];
    const int tid = threadIdx.x;
    float s = 0.0f;
    for (int i = tid; i < NBLOCKS; i += NTHREADS) s += partials[i];
#pragma unroll
    for (int off = 32; off > 0; off >>= 1) s += __shfl_down(s, off, 64);
    if ((tid & 63) == 0) wp[tid >> 6] = s;
    __syncthreads();
    if (tid == 0)
        out[0] = 1.0f - (wp[0] + wp[1] + wp[2] + wp[3]) * (1.0f / (float)N_ELEMS);
}

extern "C" void kernel_launch(void* const* d_in, const int* in_sizes, int n_in,
                              void* d_out, int out_size, void* d_ws, size_t ws_size,
                              hipStream_t stream) {
    const float* img1 = (const float*)d_in[0];
    const float* img2 = (const float*)d_in[1];
    float* out = (float*)d_out;
    float* partials = (float*)d_ws;     // NBLOCKS floats = 48 KB

    dim3 grid(GX, GY, NPLANES);
    ssim_main<<<grid, NTHREADS, 0, stream>>>(img1, img2, partials);
    ssim_final<<<1, NTHREADS, 0, stream>>>(partials, out);
}

// Round 3
// 156.404 us; speedup vs baseline: 1.7159x; 1.1385x over previous
//
#include <hip/hip_runtime.h>

#define IMG_H 512
#define IMG_W 512
#define NPLANES 48            // 16 batch * 3 channels
#define N_ELEMS (16 * 3 * 512 * 512)

#define TW 32
#define TH 32
#define NTHREADS 256
#define GX (IMG_W / TW)       // 16
#define GY (IMG_H / TH)       // 16
#define NBLOCKS (GX * GY * NPLANES)   // 12288

#define SROWS 42              // staged rows (TH + 10)
#define SCOLS 48              // staged cols: aligned 48-float window [tx0-8, tx0+40)
#define SSTRIDE 50            // stage row stride in float2 (rotates banks by 4/row)
#define RROWS 32
#define RSTRIDE 46            // r row stride in float2

#define C1f 1.0e-4f
#define C2f 9.0e-4f

typedef float v2f __attribute__((ext_vector_type(2)));

// Gaussian window exp(-(i-5)^2/4.5), normalized — hardcoded (saves 11 expf +
// divide per thread; double-precision-derived, |err| ~1e-7 vs f32 chain,
// irrelevant at 1.98e-2 threshold).
__device__ __constant__ float G[11] = {
    0.00102838f, 0.00759876f, 0.03600077f, 0.10936070f, 0.21300553f,
    0.26601173f,
    0.21300553f, 0.10936070f, 0.03600077f, 0.00759876f, 0.00102838f
};

// LDS: staging (s,d) pairs overlaid with vertical-conv results (which cross
// the barrier in registers). 23.5 KB -> 6 blocks/CU possible.
union SsimLds {
    v2f stage[SROWS * SSTRIDE];                       // 16.8 KB: (s,d) per px
    struct { v2f a[RROWS * RSTRIDE]; v2f b[RROWS * RSTRIDE]; } r;  // 23.5 KB
};

__global__ void __launch_bounds__(NTHREADS, 6) ssim_main(
    const float* __restrict__ img1, const float* __restrict__ img2,
    float* __restrict__ partials)
{
    __shared__ SsimLds u;
    __shared__ float wpart[NTHREADS / 64];

    const int tid = threadIdx.x;
    const int bx = blockIdx.x, by = blockIdx.y;
    const int plane = blockIdx.z;
    const int tx0 = bx * TW, ty0 = by * TH;
    const float* p1 = img1 + (size_t)plane * IMG_H * IMG_W;
    const float* p2 = img2 + (size_t)plane * IMG_H * IMG_W;

    // ---- Phase 1: stage (s,d) = (a+b, a-b), window x: [tx0-8, tx0+40) ----
    const bool interior = (bx > 0) & (bx < GX - 1) & (by > 0) & (by < GY - 1);
    if (interior) {
        // 42 rows x 12 float4 = 504 vector-load pairs, 2 rounds.
#pragma unroll
        for (int k = 0; k < 2; ++k) {
            int i = tid + k * NTHREADS;
            if (i < SROWS * 12) {
                int row = i / 12;
                int c4 = i - row * 12;
                size_t off = (size_t)(ty0 - 5 + row) * IMG_W + (tx0 - 8) + 4 * c4;
                float4 a = *(const float4*)(p1 + off);
                float4 b = *(const float4*)(p2 + off);
                float4 s = make_float4(a.x + b.x, a.y + b.y, a.z + b.z, a.w + b.w);
                float4 d = make_float4(a.x - b.x, a.y - b.y, a.z - b.z, a.w - b.w);
                float4* dst = (float4*)&u.stage[row * SSTRIDE + 4 * c4];
                dst[0] = make_float4(s.x, d.x, s.y, d.y);
                dst[1] = make_float4(s.z, d.z, s.w, d.w);
            }
        }
    } else {
        for (int i = tid; i < SROWS * SCOLS; i += NTHREADS) {
            int sy = i / SCOLS;
            int sx = i - sy * SCOLS;
            int gy = ty0 - 5 + sy;
            int gx = tx0 - 8 + sx;
            float a = 0.0f, b = 0.0f;
            if ((unsigned)gy < IMG_H && (unsigned)gx < IMG_W) {
                size_t idx = (size_t)gy * IMG_W + gx;
                a = p1[idx];
                b = p2[idx];
            }
            v2f sd; sd.x = a + b; sd.y = a - b;
            u.stage[sy * SSTRIDE + sx] = sd;
        }
    }
    __syncthreads();

    // ---- Phase 2: vertical conv of (s,d) and (s^2,d^2), packed fp32 ----
    // 176 active threads: 44 cols (sx in [2,46)) x 4 groups of 8 rows.
    const bool vact = tid < 176;
    const int sx = 2 + (tid % 44);
    const int vy0 = (tid / 44) * 8;
    v2f asd[8], ass[8];
    if (vact) {
#pragma unroll
        for (int k = 0; k < 8; ++k) { asd[k] = (v2f)0.0f; ass[k] = (v2f)0.0f; }
#pragma unroll
        for (int j = 0; j < 8 + 10; ++j) {           // 18 staged rows
            v2f sd = u.stage[(vy0 + j) * SSTRIDE + sx];   // one ds_read_b64
            v2f sq = sd * sd;                              // pk_mul
#pragma unroll
            for (int k = 0; k < 8; ++k) {
                int t = j - k;
                if (t >= 0 && t < 11) {                    // folds at compile time
                    asd[k] += G[t] * sd;                   // pk_fma
                    ass[k] += G[t] * sq;                   // pk_fma
                }
            }
        }
    }
    __syncthreads();     // stage reads done -> safe to overwrite with r

    if (vact) {
#pragma unroll
        for (int k = 0; k < 8; ++k) {
            u.r.a[(vy0 + k) * RSTRIDE + (sx - 2)] = asd[k];
            u.r.b[(vy0 + k) * RSTRIDE + (sx - 2)] = ass[k];
        }
    }
    __syncthreads();

    // ---- Phase 3: horizontal conv (packed) + SSIM + local sum ----
    // 256 threads x 4 outputs: y = tid>>3, x0 = (tid&7)*4.
    const int hy = tid >> 3;
    const int hx0 = (tid & 7) * 4;
    v2f osd[4], oss[4];
#pragma unroll
    for (int k = 0; k < 4; ++k) { osd[k] = (v2f)0.0f; oss[k] = (v2f)0.0f; }

#pragma unroll
    for (int j = 0; j < 4 + 10; ++j) {               // 14 columns
        v2f va = u.r.a[hy * RSTRIDE + 1 + hx0 + j];  // (conv_s, conv_d)
        v2f vb = u.r.b[hy * RSTRIDE + 1 + hx0 + j];  // (conv_ss, conv_dd)
#pragma unroll
        for (int k = 0; k < 4; ++k) {
            int t = j - k;
            if (t >= 0 && t < 11) {
                osd[k] += G[t] * va;                 // pk_fma
                oss[k] += G[t] * vb;                 // pk_fma
            }
        }
    }

    float local = 0.0f;
#pragma unroll
    for (int k = 0; k < 4; ++k) {
        float cs = osd[k].x, cd = osd[k].y;
        float css = oss[k].x, cdd = oss[k].y;
        float cs2 = cs * cs, cd2 = cd * cd;
        float mu12 = 0.25f * (cs2 - cd2);     // mu1*mu2
        float musq = 0.50f * (cs2 + cd2);     // mu1^2 + mu2^2
        float e12  = 0.25f * (css - cdd);     // E[ab]
        float esum = 0.50f * (css + cdd);     // E[a^2] + E[b^2]
        float sg12  = e12 - mu12;
        float sgsum = esum - musq;
        float num = (2.0f * mu12 + C1f) * (2.0f * sg12 + C2f);
        float den = (musq + C1f) * (sgsum + C2f);
        local += num * __builtin_amdgcn_rcpf(den);   // v_rcp: ~1e-7 rel err
    }

    // ---- Block reduction -> one partial per block ----
#pragma unroll
    for (int off = 32; off > 0; off >>= 1) local += __shfl_down(local, off, 64);
    if ((tid & 63) == 0) wpart[tid >> 6] = local;
    __syncthreads();
    if (tid == 0) {
        int bid = blockIdx.x + GX * (blockIdx.y + GY * blockIdx.z);
        partials[bid] = wpart[0] + wpart[1] + wpart[2] + wpart[3];
    }
}

__global__ void ssim_final(const float* __restrict__ partials,
                           float* __restrict__ out)
{
    __shared__ float wp[4];
    const int tid = threadIdx.x;
    const float4* p4 = (const float4*)partials;      // 3072 float4
    float s = 0.0f;
#pragma unroll
    for (int k = 0; k < 12; ++k) {                   // 12 independent b128 loads
        float4 v = p4[tid + k * NTHREADS];
        s += (v.x + v.y) + (v.z + v.w);
    }
#pragma unroll
    for (int off = 32; off > 0; off >>= 1) s += __shfl_down(s, off, 64);
    if ((tid & 63) == 0) wp[tid >> 6] = s;
    __syncthreads();
    if (tid == 0)
        out[0] = 1.0f - (wp[0] + wp[1] + wp[2] + wp[3]) * (1.0f / (float)N_ELEMS);
}

extern "C" void kernel_launch(void* const* d_in, const int* in_sizes, int n_in,
                              void* d_out, int out_size, void* d_ws, size_t ws_size,
                              hipStream_t stream) {
    const float* img1 = (const float*)d_in[0];
    const float* img2 = (const float*)d_in[1];
    float* out = (float*)d_out;
    float* partials = (float*)d_ws;     // NBLOCKS floats = 48 KB

    dim3 grid(GX, GY, NPLANES);
    ssim_main<<<grid, NTHREADS, 0, stream>>>(img1, img2, partials);
    ssim_final<<<1, NTHREADS, 0, stream>>>(partials, out);
}

// Round 4
// 152.433 us; speedup vs baseline: 1.7606x; 1.0261x over previous
//
#include <hip/hip_runtime.h>

#define IMG_H 512
#define IMG_W 512
#define NPLANES 48            // 16 batch * 3 channels
#define N_ELEMS (16 * 3 * 512 * 512)

#define TW 32
#define TH 32
#define NTHREADS 256
#define GX (IMG_W / TW)       // 16
#define GY (IMG_H / TH)       // 16
#define NBLOCKS (GX * GY * NPLANES)   // 12288

#define SROWS 42              // staged rows (TH + 10)
#define SCOLS 48              // staged cols: aligned window [tx0-8, tx0+40)
#define SSTRIDE 48            // stage row stride in v2f (no pad needed)
#define RSTRIDE 43            // r row stride in v2f (86 dwords -> even banks spread, 2-way=free)

#define C1f 1.0e-4f
#define C2f 9.0e-4f

typedef float v2f __attribute__((ext_vector_type(2)));

// Force packed fp32 FMA (v_pk_fma_f32): plain a+=w*v can scalarize; the
// explicit fma form selects VOP3P packed math on gfx950.
__device__ __forceinline__ v2f pkfma(float w, v2f v, v2f acc) {
    v2f wv = {w, w};
    return __builtin_elementwise_fma(wv, v, acc);
}

// LDS: staging (s,d) pairs overlaid with vertical-conv results (which cross
// the barrier in registers). max(16128, 22016) = 22.0 KB -> 7 blocks/CU.
union SsimLds {
    v2f stage[SROWS * SSTRIDE];                               // 16128 B
    struct { v2f a[TH * RSTRIDE]; v2f b[TH * RSTRIDE]; } r;   // 22016 B
};

__global__ void __launch_bounds__(NTHREADS, 7) ssim_main(
    const float* __restrict__ img1, const float* __restrict__ img2,
    float* __restrict__ partials)
{
    __shared__ SsimLds u;
    __shared__ float wpart[NTHREADS / 64];

    const int tid = threadIdx.x;
    const int bx = blockIdx.x, by = blockIdx.y;
    const int plane = blockIdx.z;
    const int tx0 = bx * TW, ty0 = by * TH;
    const float* p1 = img1 + (size_t)plane * IMG_H * IMG_W;
    const float* p2 = img2 + (size_t)plane * IMG_H * IMG_W;

    // Gaussian window exp(-(i-5)^2/4.5), normalized — compile-time constants.
    constexpr float G[11] = {
        0.00102838f, 0.00759876f, 0.03600077f, 0.10936070f, 0.21300553f,
        0.26601173f,
        0.21300553f, 0.10936070f, 0.03600077f, 0.00759876f, 0.00102838f
    };

    // ---- Phase 1: stage (s,d) = (a+b, a-b), window x: [tx0-8, tx0+40) ----
    const bool interior = (bx > 0) & (bx < GX - 1) & (by > 0) & (by < GY - 1);
    if (interior) {
        // 42 rows x 12 float4 = 504 vector-load pairs, 2 rounds.
#pragma unroll
        for (int k = 0; k < 2; ++k) {
            int i = tid + k * NTHREADS;
            if (i < SROWS * 12) {
                int row = i / 12;
                int c4 = i - row * 12;
                size_t off = (size_t)(ty0 - 5 + row) * IMG_W + (tx0 - 8) + 4 * c4;
                float4 a = *(const float4*)(p1 + off);
                float4 b = *(const float4*)(p2 + off);
                float4* dst = (float4*)&u.stage[row * SSTRIDE + 4 * c4];
                dst[0] = make_float4(a.x + b.x, a.x - b.x, a.y + b.y, a.y - b.y);
                dst[1] = make_float4(a.z + b.z, a.z - b.z, a.w + b.w, a.w - b.w);
            }
        }
    } else {
        for (int i = tid; i < SROWS * SCOLS; i += NTHREADS) {
            int sy = i / SCOLS;
            int sx = i - sy * SCOLS;
            int gy = ty0 - 5 + sy;
            int gx = tx0 - 8 + sx;
            float a = 0.0f, b = 0.0f;
            if ((unsigned)gy < IMG_H && (unsigned)gx < IMG_W) {
                size_t idx = (size_t)gy * IMG_W + gx;
                a = p1[idx];
                b = p2[idx];
            }
            v2f sd; sd.x = a + b; sd.y = a - b;
            u.stage[sy * SSTRIDE + sx] = sd;
        }
    }
    __syncthreads();

    // ---- Phase 2: vertical conv of (s,d) and (s^2,d^2), packed fp32 ----
    // 168 active threads: 42 cols (x in [-5,37), sx in [3,45)) x 4 groups of 8 rows.
    const bool vact = tid < 168;
    const int sx = 3 + tid % 42;
    const int vy0 = (tid / 42) * 8;
    v2f asd[8], ass[8];
    if (vact) {
#pragma unroll
        for (int k = 0; k < 8; ++k) { asd[k] = (v2f)0.0f; ass[k] = (v2f)0.0f; }
#pragma unroll
        for (int j = 0; j < 18; ++j) {                    // 18 staged rows
            v2f sd = u.stage[(vy0 + j) * SSTRIDE + sx];   // ds_read_b64
            v2f sq = sd * sd;                             // pk_mul
#pragma unroll
            for (int k = 0; k < 8; ++k) {
                int t = j - k;
                if (t >= 0 && t < 11) {                   // folds at compile time
                    asd[k] = pkfma(G[t], sd, asd[k]);
                    ass[k] = pkfma(G[t], sq, ass[k]);
                }
            }
        }
    }
    __syncthreads();     // stage reads done -> safe to overwrite with r

    if (vact) {
#pragma unroll
        for (int k = 0; k < 8; ++k) {
            u.r.a[(vy0 + k) * RSTRIDE + (sx - 3)] = asd[k];
            u.r.b[(vy0 + k) * RSTRIDE + (sx - 3)] = ass[k];
        }
    }
    __syncthreads();

    // ---- Phase 3: horizontal conv (packed) + SSIM + local sum ----
    // 256 threads x 4 outputs: y = tid>>3, x0 = (tid&7)*4.
    const int hy = tid >> 3;
    const int hx0 = (tid & 7) * 4;
    v2f osd[4], oss[4];
#pragma unroll
    for (int k = 0; k < 4; ++k) { osd[k] = (v2f)0.0f; oss[k] = (v2f)0.0f; }

#pragma unroll
    for (int j = 0; j < 14; ++j) {                   // 14 r-columns feed 4 outputs
        v2f va = u.r.a[hy * RSTRIDE + hx0 + j];      // (conv_s,  conv_d)
        v2f vb = u.r.b[hy * RSTRIDE + hx0 + j];      // (conv_ss, conv_dd)
#pragma unroll
        for (int k = 0; k < 4; ++k) {
            int t = j - k;
            if (t >= 0 && t < 11) {
                osd[k] = pkfma(G[t], va, osd[k]);
                oss[k] = pkfma(G[t], vb, oss[k]);
            }
        }
    }

    float local = 0.0f;
#pragma unroll
    for (int k = 0; k < 4; ++k) {
        v2f sd2 = osd[k] * osd[k];            // (cs^2, cd^2) pk_mul
        float cs2 = sd2.x, cd2 = sd2.y;
        float css = oss[k].x, cdd = oss[k].y;
        float mu12 = 0.25f * (cs2 - cd2);     // mu1*mu2
        float musq = 0.50f * (cs2 + cd2);     // mu1^2 + mu2^2
        float e12  = 0.25f * (css - cdd);     // E[ab]
        float esum = 0.50f * (css + cdd);     // E[a^2] + E[b^2]
        float sg12  = e12 - mu12;
        float sgsum = esum - musq;
        float num = (2.0f * mu12 + C1f) * (2.0f * sg12 + C2f);
        float den = (musq + C1f) * (sgsum + C2f);
        local += num * __builtin_amdgcn_rcpf(den);   // ~1e-7 rel err, fine at 2e-2
    }

    // ---- Block reduction -> one partial per block ----
#pragma unroll
    for (int off = 32; off > 0; off >>= 1) local += __shfl_down(local, off, 64);
    if ((tid & 63) == 0) wpart[tid >> 6] = local;
    __syncthreads();
    if (tid == 0) {
        int bid = blockIdx.x + GX * (blockIdx.y + GY * blockIdx.z);
        partials[bid] = wpart[0] + wpart[1] + wpart[2] + wpart[3];
    }
}

__global__ void ssim_final(const float* __restrict__ partials,
                           float* __restrict__ out)
{
    __shared__ float wp[4];
    const int tid = threadIdx.x;
    const float4* p4 = (const float4*)partials;      // 3072 float4
    float s = 0.0f;
#pragma unroll
    for (int k = 0; k < 12; ++k) {                   // 12 independent b128 loads
        float4 v = p4[tid + k * NTHREADS];
        s += (v.x + v.y) + (v.z + v.w);
    }
#pragma unroll
    for (int off = 32; off > 0; off >>= 1) s += __shfl_down(s, off, 64);
    if ((tid & 63) == 0) wp[tid >> 6] = s;
    __syncthreads();
    if (tid == 0)
        out[0] = 1.0f - (wp[0] + wp[1] + wp[2] + wp[3]) * (1.0f / (float)N_ELEMS);
}

extern "C" void kernel_launch(void* const* d_in, const int* in_sizes, int n_in,
                              void* d_out, int out_size, void* d_ws, size_t ws_size,
                              hipStream_t stream) {
    const float* img1 = (const float*)d_in[0];
    const float* img2 = (const float*)d_in[1];
    float* out = (float*)d_out;
    float* partials = (float*)d_ws;     // NBLOCKS floats = 48 KB

    dim3 grid(GX, GY, NPLANES);
    ssim_main<<<grid, NTHREADS, 0, stream>>>(img1, img2, partials);
    ssim_final<<<1, NTHREADS, 0, stream>>>(partials, out);
}

// Round 5
// 150.163 us; speedup vs baseline: 1.7873x; 1.0151x over previous
//
#include <hip/hip_runtime.h>

#define IMG_H 512
#define IMG_W 512
#define NPLANES 48            // 16 batch * 3 channels
#define N_ELEMS (16 * 3 * 512 * 512)

#define TW 32
#define TH 32
#define NTHREADS 256
#define GX (IMG_W / TW)       // 16
#define GY (IMG_H / TH)       // 16
#define NBLOCKS (GX * GY * NPLANES)   // 12288

#define RS4 43                // r row stride in float4 (odd -> b128 bank floor)

#define C1f 1.0e-4f
#define C2f 9.0e-4f

typedef float v2f __attribute__((ext_vector_type(2)));

// Packed fp32 FMA.
__device__ __forceinline__ v2f pkfma(float w, v2f v, v2f acc) {
    v2f wv = {w, w};
    return __builtin_elementwise_fma(wv, v, acc);
}

__global__ void __launch_bounds__(NTHREADS, 7) ssim_main(
    const float* __restrict__ img1, const float* __restrict__ img2,
    float* __restrict__ partials)
{
    // Single LDS buffer: vertical-conv results, interleaved
    // (conv_s, conv_d, conv_ss, conv_dd) per pixel. 32*43*16 = 22016 B.
    __shared__ float4 r[TH * RS4];
    __shared__ float wpart[NTHREADS / 64];

    const int tid = threadIdx.x;

    // XCD swizzle: blockIdx->XCD is round-robin (%8); map so each XCD gets
    // 6 contiguous planes -> halo re-reads hit that XCD's L2 (2MB < 4MB).
    const int work = (blockIdx.x & 7) * (NBLOCKS / 8) + (blockIdx.x >> 3);
    const int plane = work >> 8;          // /256 tiles per plane
    const int rem = work & 255;
    const int by = rem >> 4, bx = rem & 15;
    const int tx0 = bx * TW, ty0 = by * TH;
    const float* p1 = img1 + (size_t)plane * IMG_H * IMG_W;
    const float* p2 = img2 + (size_t)plane * IMG_H * IMG_W;

    // Gaussian window exp(-(i-5)^2/4.5), normalized — compile-time constants.
    constexpr float G[11] = {
        0.00102838f, 0.00759876f, 0.03600077f, 0.10936070f, 0.21300553f,
        0.26601173f,
        0.21300553f, 0.10936070f, 0.03600077f, 0.00759876f, 0.00102838f
    };

    // ---- Phase A: vertical conv of (s,d)=(a+b,a-b) and (s^2,d^2),
    //      read DIRECTLY from global (coalesced: lane = column).
    // 168 active threads: col c = tid%42 (gx = tx0-5+c), group g = tid/42
    // produces output rows [8g, 8g+8) from input rows gy0+j, j in [0,18).
    if (tid < 168) {
        const int c = tid % 42;
        const int g = tid / 42;
        const int gx = tx0 - 5 + c;
        const int gy0 = ty0 + 8 * g - 5;

        v2f asd[8], ass[8];
#pragma unroll
        for (int k = 0; k < 8; ++k) { asd[k] = (v2f)0.0f; ass[k] = (v2f)0.0f; }

        const bool inter = ((unsigned)gx < IMG_W) & (gy0 >= 0) &
                           (gy0 + 17 < IMG_H);
        if (inter) {
            const float* pa = p1 + (size_t)gy0 * IMG_W + gx;
            const float* pb = p2 + (size_t)gy0 * IMG_W + gx;
#pragma unroll
            for (int j = 0; j < 18; ++j) {
                float a = pa[j * IMG_W];
                float b = pb[j * IMG_W];
                v2f sd; sd.x = a + b; sd.y = a - b;
                v2f sq = sd * sd;
#pragma unroll
                for (int k = 0; k < 8; ++k) {
                    int t = j - k;
                    if (t >= 0 && t < 11) {
                        asd[k] = pkfma(G[t], sd, asd[k]);
                        ass[k] = pkfma(G[t], sq, ass[k]);
                    }
                }
            }
        } else {
            const int cx = min(max(gx, 0), IMG_W - 1);
            const float mx = ((unsigned)gx < IMG_W) ? 1.0f : 0.0f;
#pragma unroll
            for (int j = 0; j < 18; ++j) {
                int gy = gy0 + j;
                int cy = min(max(gy, 0), IMG_H - 1);
                float m = ((unsigned)gy < IMG_H) ? mx : 0.0f;
                size_t off = (size_t)cy * IMG_W + cx;
                float a = p1[off] * m;
                float b = p2[off] * m;
                v2f sd; sd.x = a + b; sd.y = a - b;
                v2f sq = sd * sd;
#pragma unroll
                for (int k = 0; k < 8; ++k) {
                    int t = j - k;
                    if (t >= 0 && t < 11) {
                        asd[k] = pkfma(G[t], sd, asd[k]);
                        ass[k] = pkfma(G[t], sq, ass[k]);
                    }
                }
            }
        }
#pragma unroll
        for (int k = 0; k < 8; ++k)
            r[(8 * g + k) * RS4 + c] =
                make_float4(asd[k].x, asd[k].y, ass[k].x, ass[k].y);
    }
    __syncthreads();

    // ---- Phase B: horizontal conv + SSIM. 128 threads x 8 outputs:
    // hy = tid>>2 (0..31), x0 = (tid&3)*8; reads r cols [x0, x0+18).
    float local = 0.0f;
    if (tid < 128) {
        const int hy = tid >> 2;
        const int x0 = (tid & 3) * 8;
        v2f osd[8], oss[8];
#pragma unroll
        for (int k = 0; k < 8; ++k) { osd[k] = (v2f)0.0f; oss[k] = (v2f)0.0f; }

#pragma unroll
        for (int j = 0; j < 18; ++j) {
            float4 v = r[hy * RS4 + x0 + j];      // one ds_read_b128
            v2f va; va.x = v.x; va.y = v.y;       // (conv_s,  conv_d)
            v2f vb; vb.x = v.z; vb.y = v.w;       // (conv_ss, conv_dd)
#pragma unroll
            for (int k = 0; k < 8; ++k) {
                int t = j - k;
                if (t >= 0 && t < 11) {
                    osd[k] = pkfma(G[t], va, osd[k]);
                    oss[k] = pkfma(G[t], vb, oss[k]);
                }
            }
        }

#pragma unroll
        for (int k = 0; k < 8; ++k) {
            v2f sd2 = osd[k] * osd[k];            // (cs^2, cd^2)
            float cs2 = sd2.x, cd2 = sd2.y;
            float css = oss[k].x, cdd = oss[k].y;
            float mu12 = 0.25f * (cs2 - cd2);     // mu1*mu2
            float musq = 0.50f * (cs2 + cd2);     // mu1^2 + mu2^2
            float e12  = 0.25f * (css - cdd);     // E[ab]
            float esum = 0.50f * (css + cdd);     // E[a^2] + E[b^2]
            float sg12  = e12 - mu12;
            float sgsum = esum - musq;
            float num = (2.0f * mu12 + C1f) * (2.0f * sg12 + C2f);
            float den = (musq + C1f) * (sgsum + C2f);
            local += num * __builtin_amdgcn_rcpf(den);  // ~1e-7 rel err
        }
    }

    // ---- Block reduction -> one partial per block ----
#pragma unroll
    for (int off = 32; off > 0; off >>= 1) local += __shfl_down(local, off, 64);
    if ((tid & 63) == 0) wpart[tid >> 6] = local;
    __syncthreads();
    if (tid == 0)
        partials[blockIdx.x] = wpart[0] + wpart[1] + wpart[2] + wpart[3];
}

__global__ void ssim_final(const float* __restrict__ partials,
                           float* __restrict__ out)
{
    __shared__ float wp[4];
    const int tid = threadIdx.x;
    const float4* p4 = (const float4*)partials;      // 3072 float4
    float s = 0.0f;
#pragma unroll
    for (int k = 0; k < 12; ++k) {                   // independent b128 loads
        float4 v = p4[tid + k * NTHREADS];
        s += (v.x + v.y) + (v.z + v.w);
    }
#pragma unroll
    for (int off = 32; off > 0; off >>= 1) s += __shfl_down(s, off, 64);
    if ((tid & 63) == 0) wp[tid >> 6] = s;
    __syncthreads();
    if (tid == 0)
        out[0] = 1.0f - (wp[0] + wp[1] + wp[2] + wp[3]) * (1.0f / (float)N_ELEMS);
}

extern "C" void kernel_launch(void* const* d_in, const int* in_sizes, int n_in,
                              void* d_out, int out_size, void* d_ws, size_t ws_size,
                              hipStream_t stream) {
    const float* img1 = (const float*)d_in[0];
    const float* img2 = (const float*)d_in[1];
    float* out = (float*)d_out;
    float* partials = (float*)d_ws;     // NBLOCKS floats = 48 KB

    ssim_main<<<NBLOCKS, NTHREADS, 0, stream>>>(img1, img2, partials);
    ssim_final<<<1, NTHREADS, 0, stream>>>(partials, out);
}